// Round 1
// baseline (9845.544 us; speedup 1.0000x reference)
//
#include <hip/hip_runtime.h>
#include <cstdint>
#include <cstddef>

#define NN 500

// ---------------------------------------------------------------------------
// adp = softmax(relu(E1 @ E2), axis=1)   E1:[500,10] E2:[10,500] -> adp[500,500]
__global__ __launch_bounds__(256) void adp_kernel(const float* __restrict__ e1,
                                                  const float* __restrict__ e2,
                                                  float* __restrict__ adp) {
  int r = blockIdx.x;
  int tid = threadIdx.x;
  __shared__ float red[256];
  __shared__ float e1row[16];
  if (tid < 10) e1row[tid] = e1[r * 10 + tid];
  __syncthreads();
  float z0, z1 = 0.f;
  {
    float acc = 0.f;
#pragma unroll
    for (int k = 0; k < 10; k++) acc += e1row[k] * e2[k * NN + tid];
    z0 = fmaxf(acc, 0.f);
  }
  bool has1 = (tid + 256) < NN;
  if (has1) {
    float acc = 0.f;
#pragma unroll
    for (int k = 0; k < 10; k++) acc += e1row[k] * e2[k * NN + tid + 256];
    z1 = fmaxf(acc, 0.f);
  }
  float mx = has1 ? fmaxf(z0, z1) : z0;
  red[tid] = mx;
  __syncthreads();
  for (int s = 128; s > 0; s >>= 1) {
    if (tid < s) red[tid] = fmaxf(red[tid], red[tid + s]);
    __syncthreads();
  }
  mx = red[0];
  __syncthreads();
  float ex0 = __expf(z0 - mx);
  float ex1 = has1 ? __expf(z1 - mx) : 0.f;
  red[tid] = ex0 + ex1;
  __syncthreads();
  for (int s = 128; s > 0; s >>= 1) {
    if (tid < s) red[tid] += red[tid + s];
    __syncthreads();
  }
  float inv = 1.f / red[0];
  adp[r * NN + tid] = ex0 * inv;
  if (has1) adp[r * NN + tid + 256] = ex1 * inv;
}

// ---------------------------------------------------------------------------
// h0[bb,c,t,n] = start_w[c,0]*x[b,0,n,t] + start_w[c,1]*x[b,1,n,t] + start_b[c]
__global__ __launch_bounds__(256) void start_conv_kernel(const float* __restrict__ x,
    const float* __restrict__ w, const float* __restrict__ bias,
    float* __restrict__ h0, int b0) {
  int nc = blockIdx.x, t = blockIdx.y, bb = blockIdx.z;
  int n = nc * 256 + threadIdx.x;
  if (n >= NN) return;
  int babs = b0 + bb;
  float x0 = x[(((size_t)babs * 2 + 0) * NN + n) * 256 + t];
  float x1 = x[(((size_t)babs * 2 + 1) * NN + n) * 256 + t];
#pragma unroll
  for (int c = 0; c < 32; c++) {
    h0[(((size_t)bb * 32 + c) * 256 + t) * NN + n] = bias[c] + w[c * 2] * x0 + w[c * 2 + 1] * x1;
  }
}

// ---------------------------------------------------------------------------
// Dilated conv + tanh*sigmoid gating on compact time axis:
// FG[bb,c,j,n] = tanh(Wf0 h[2j] + Wf1 h[2j+1] + bf) * sigmoid(Wg0 h[2j] + Wg1 h[2j+1] + bg)
// Also writes the skip tap (j == L-1) into tapL[b,c,n].
__global__ __launch_bounds__(256) void dconv_kernel(const float* __restrict__ hprev,
    const float* __restrict__ fw, const float* __restrict__ fb,
    const float* __restrict__ gw, const float* __restrict__ gb,
    float* __restrict__ FG, float* __restrict__ tapL,
    int Lp, int L, int b0) {
  int nc = blockIdx.x, j = blockIdx.y, bb = blockIdx.z;
  int n = nc * 256 + threadIdx.x;
  if (n >= NN) return;
  float accf[32], accg[32];
#pragma unroll
  for (int c = 0; c < 32; c++) { accf[c] = fb[c]; accg[c] = gb[c]; }
  size_t base = ((size_t)(bb * 32) * Lp + 2 * j) * NN + n;
  size_t cs = (size_t)Lp * NN;
#pragma unroll 4
  for (int cp = 0; cp < 32; cp++) {
    float v0 = hprev[base + cp * cs];
    float v1 = hprev[base + cp * cs + NN];
    const float* fwp = fw + cp * 2;   // weight layout [c][cp][tap] -> fwp[c*64 + tap]
    const float* gwp = gw + cp * 2;
#pragma unroll
    for (int c = 0; c < 32; c++) {
      accf[c] = fmaf(fwp[c * 64], v0, accf[c]);
      accf[c] = fmaf(fwp[c * 64 + 1], v1, accf[c]);
      accg[c] = fmaf(gwp[c * 64], v0, accg[c]);
      accg[c] = fmaf(gwp[c * 64 + 1], v1, accg[c]);
    }
  }
  bool last = (j == L - 1);
  size_t obase = ((size_t)(bb * 32) * L + j) * NN + n;
  size_t ocs = (size_t)L * NN;
  size_t tbase = ((size_t)(b0 + bb) * 32) * NN + n;
#pragma unroll 4
  for (int c = 0; c < 32; c++) {
    float E = __expf(2.f * accf[c]);
    float th = 1.f - 2.f / (E + 1.f);          // tanh, saturates safely at +-1
    float sg = 1.f / (1.f + __expf(-accg[c])); // sigmoid
    float v = th * sg;
    FG[obase + c * ocs] = v;
    if (last) tapL[tbase + (size_t)c * NN] = v;
  }
}

// ---------------------------------------------------------------------------
// Channel mixes of the GCN, exploiting (Wc X) A == Wc (X A):
// VAR=0: H = W0*FG + gcn_b + residual(hprev[2j+1]),  P1 = W1*FG,  P2 = W2*FG
// VAR=1: P1 = W3*FG,  P2 = W4*FG
template <int VAR>
__global__ __launch_bounds__(256) void chanmix_kernel(const float* __restrict__ FG,
    const float* __restrict__ gw, const float* __restrict__ gb,
    const float* __restrict__ hprev,
    float* __restrict__ H, float* __restrict__ P1, float* __restrict__ P2,
    int L, int Lp) {
  int nc = blockIdx.x, j = blockIdx.y, bb = blockIdx.z;
  int n = nc * 256 + threadIdx.x;
  if (n >= NN) return;
  float fgv[32];
  size_t base = ((size_t)(bb * 32) * L + j) * NN + n;
  size_t cs = (size_t)L * NN;
#pragma unroll 8
  for (int cp = 0; cp < 32; cp++) fgv[cp] = FG[base + cp * cs];
#pragma unroll 4
  for (int c = 0; c < 32; c++) {
    const float* wr = gw + c * 160;
    if (VAR == 0) {
      float a0 = gb[c], a1 = 0.f, a2 = 0.f;
#pragma unroll
      for (int cp = 0; cp < 32; cp++) {
        float f = fgv[cp];
        a0 = fmaf(wr[cp], f, a0);
        a1 = fmaf(wr[32 + cp], f, a1);
        a2 = fmaf(wr[64 + cp], f, a2);
      }
      a0 += hprev[((size_t)(bb * 32 + c) * Lp + 2 * j + 1) * NN + n]; // residual
      H[base + c * cs] = a0;
      P1[base + c * cs] = a1;
      P2[base + c * cs] = a2;
    } else {
      float a3 = 0.f, a4 = 0.f;
#pragma unroll
      for (int cp = 0; cp < 32; cp++) {
        float f = fgv[cp];
        a3 = fmaf(wr[96 + cp], f, a3);
        a4 = fmaf(wr[128 + cp], f, a4);
      }
      P1[base + c * cs] = a3;
      P2[base + c * cs] = a4;
    }
  }
}

// ---------------------------------------------------------------------------
// Cout[m,n] = sum_k A[m,k]*B[k,n] + Cin[m,n]   (optional BN epilogue on last GEMM)
// 128x128 block tile, 8x8 per thread, BK=16 staged in LDS.
__global__ __launch_bounds__(256) void gemm_acc(const float* __restrict__ A,
    const float* __restrict__ Bmat, const float* Cin, float* Cout,
    int M, int K, int Nw,
    const float* __restrict__ bng, const float* __restrict__ bnb, int Lc) {
  __shared__ float As[16][132];  // [k][m], +4 pad
  __shared__ float Bs[16][132];  // [k][n]
  int tid = threadIdx.x;
  int bm = blockIdx.y * 128, bn = blockIdx.x * 128;
  int ty = tid >> 4, tx = tid & 15;
  float acc[8][8];
#pragma unroll
  for (int i = 0; i < 8; i++)
#pragma unroll
    for (int j2 = 0; j2 < 8; j2++) acc[i][j2] = 0.f;

  int kTiles = (K + 15) / 16;
  for (int kt = 0; kt < kTiles; kt++) {
    int k0 = kt * 16;
    {
      int kl = tid & 15, m8 = tid >> 4;
      int k = k0 + kl;
      bool kok = k < K;
#pragma unroll
      for (int r = 0; r < 8; r++) {
        int m = bm + m8 * 8 + r;
        As[kl][m8 * 8 + r] = (kok && m < M) ? A[(size_t)m * K + k] : 0.f;
      }
    }
    {
      int n4 = (tid & 31) * 4;
      int kl = tid >> 5;
#pragma unroll
      for (int h = 0; h < 2; h++) {
        int k = k0 + kl + h * 8;
        int n = bn + n4;
        float4 v = make_float4(0.f, 0.f, 0.f, 0.f);
        if (k < K && n < Nw) v = *reinterpret_cast<const float4*>(Bmat + (size_t)k * Nw + n);
        *reinterpret_cast<float4*>(&Bs[kl + h * 8][n4]) = v;
      }
    }
    __syncthreads();
#pragma unroll
    for (int k = 0; k < 16; k++) {
      float4 a0 = *reinterpret_cast<const float4*>(&As[k][ty * 8]);
      float4 a1 = *reinterpret_cast<const float4*>(&As[k][ty * 8 + 4]);
      float4 b0 = *reinterpret_cast<const float4*>(&Bs[k][tx * 8]);
      float4 b1 = *reinterpret_cast<const float4*>(&Bs[k][tx * 8 + 4]);
      float av[8] = {a0.x, a0.y, a0.z, a0.w, a1.x, a1.y, a1.z, a1.w};
      float bv[8] = {b0.x, b0.y, b0.z, b0.w, b1.x, b1.y, b1.z, b1.w};
#pragma unroll
      for (int i = 0; i < 8; i++)
#pragma unroll
        for (int j2 = 0; j2 < 8; j2++) acc[i][j2] = fmaf(av[i], bv[j2], acc[i][j2]);
    }
    __syncthreads();
  }
  bool dobn = (bng != nullptr);
#pragma unroll
  for (int i = 0; i < 8; i++) {
    int m = bm + ty * 8 + i;
    if (m >= M) continue;
    float scale = 1.f, bias = 0.f;
    if (dobn) {
      int c = (m / Lc) & 31;  // m = (bb*32+c)*L + j  ->  (m/L)%32 == c
      scale = bng[c] * rsqrtf(1.0f + 1e-5f);
      bias = bnb[c];
    }
#pragma unroll
    for (int j2 = 0; j2 < 8; j2++) {
      int n = bn + tx * 8 + j2;
      if (n < Nw) {
        float v = acc[i][j2] + Cin[(size_t)m * Nw + n];
        if (dobn) v = v * scale + bias;
        Cout[(size_t)m * Nw + n] = v;
      }
    }
  }
}

// ---------------------------------------------------------------------------
// skip = sum_i (skip_w[i] @ tap[i] + skip_b[i]); out = end2(relu(end1(relu(skip))))
// One block per (b, 4 n-values).
__global__ __launch_bounds__(256) void final_kernel(const float* __restrict__ tap,
    const float* __restrict__ skw, const float* __restrict__ skb,
    const float* __restrict__ e1w, const float* __restrict__ e1b,
    const float* __restrict__ e2w, const float* __restrict__ e2b,
    float* __restrict__ out) {
  __shared__ float tapS[256][4];
  __shared__ float skS[256][4];
  __shared__ float e1S[512][4];
  int tid = threadIdx.x;
  int b = blockIdx.y;
  int n0 = blockIdx.x * 4;
  {
    int i = tid >> 5, c = tid & 31;
    const float* tp = tap + (((size_t)i * 8 + b) * 32 + c) * NN + n0;
#pragma unroll
    for (int v = 0; v < 4; v++) tapS[tid][v] = tp[v];
  }
  __syncthreads();
  {
    float bsum = 0.f;
#pragma unroll
    for (int i2 = 0; i2 < 8; i2++) bsum += skb[i2 * 256 + tid];
    float acc0 = bsum, acc1 = bsum, acc2 = bsum, acc3 = bsum;
#pragma unroll 2
    for (int i2 = 0; i2 < 8; i2++) {
      const float* wr = skw + ((size_t)i2 * 256 + tid) * 32;
#pragma unroll
      for (int cp = 0; cp < 32; cp++) {
        float w = wr[cp];
        acc0 = fmaf(w, tapS[i2 * 32 + cp][0], acc0);
        acc1 = fmaf(w, tapS[i2 * 32 + cp][1], acc1);
        acc2 = fmaf(w, tapS[i2 * 32 + cp][2], acc2);
        acc3 = fmaf(w, tapS[i2 * 32 + cp][3], acc3);
      }
    }
    skS[tid][0] = fmaxf(acc0, 0.f);
    skS[tid][1] = fmaxf(acc1, 0.f);
    skS[tid][2] = fmaxf(acc2, 0.f);
    skS[tid][3] = fmaxf(acc3, 0.f);
  }
  __syncthreads();
#pragma unroll
  for (int h = 0; h < 2; h++) {
    int k = tid + h * 256;
    float bv = e1b[k];
    float acc0 = bv, acc1 = bv, acc2 = bv, acc3 = bv;
    const float* wr = e1w + (size_t)k * 256;
#pragma unroll 4
    for (int o = 0; o < 256; o++) {
      float w = wr[o];
      acc0 = fmaf(w, skS[o][0], acc0);
      acc1 = fmaf(w, skS[o][1], acc1);
      acc2 = fmaf(w, skS[o][2], acc2);
      acc3 = fmaf(w, skS[o][3], acc3);
    }
    e1S[k][0] = fmaxf(acc0, 0.f);
    e1S[k][1] = fmaxf(acc1, 0.f);
    e1S[k][2] = fmaxf(acc2, 0.f);
    e1S[k][3] = fmaxf(acc3, 0.f);
  }
  __syncthreads();
  if (tid < 48) {
    int q = tid >> 2, v = tid & 3;
    float acc = e2b[q];
    const float* wr = e2w + (size_t)q * 512;
#pragma unroll 8
    for (int k = 0; k < 512; k++) acc = fmaf(wr[k], e1S[k][v], acc);
    out[((size_t)b * 12 + q) * NN + n0 + v] = acc;
  }
}

// ---------------------------------------------------------------------------
extern "C" void kernel_launch(void* const* d_in, const int* in_sizes, int n_in,
                              void* d_out, int out_size, void* d_ws, size_t ws_size,
                              hipStream_t stream) {
  const float* x       = (const float*)d_in[0];
  const float* A0      = (const float*)d_in[1];
  const float* start_w = (const float*)d_in[2];
  const float* start_b = (const float*)d_in[3];
  const float* filt_w  = (const float*)d_in[4];
  const float* filt_b  = (const float*)d_in[5];
  const float* gate_w  = (const float*)d_in[6];
  const float* gate_b  = (const float*)d_in[7];
  const float* skip_w  = (const float*)d_in[8];
  const float* skip_b  = (const float*)d_in[9];
  const float* gcn_w   = (const float*)d_in[10];
  const float* gcn_b   = (const float*)d_in[11];
  const float* bn_g    = (const float*)d_in[12];
  const float* bn_b    = (const float*)d_in[13];
  const float* nv1     = (const float*)d_in[14];
  const float* nv2     = (const float*)d_in[15];
  const float* e1w     = (const float*)d_in[16];
  const float* e1b     = (const float*)d_in[17];
  const float* e2w     = (const float*)d_in[18];
  const float* e2b     = (const float*)d_in[19];
  float* out = (float*)d_out;

  char* ws = (char*)d_ws;
  size_t off = 0;
  auto alloc = [&](size_t bytes) -> float* {
    float* p = (float*)(ws + off);
    off += (bytes + 255) & ~(size_t)255;
    return p;
  };
  float* adp = alloc((size_t)NN * NN * 4);
  float* tap = alloc((size_t)8 * 8 * 32 * NN * 4);
  size_t fixed = off;
  // per-batch-group buffers: hA (L=256) + hB/FG/P1/P2 (L=128)
  int g = 8;
  while (g > 1 && fixed + (size_t)g * 49152000ull + 8192 > ws_size) g >>= 1;
  float* hA = alloc((size_t)g * 32 * 256 * NN * 4);
  float* hB = alloc((size_t)g * 32 * 128 * NN * 4);
  float* FG = alloc((size_t)g * 32 * 128 * NN * 4);
  float* P1 = alloc((size_t)g * 32 * 128 * NN * 4);
  float* P2 = alloc((size_t)g * 32 * 128 * NN * 4);

  adp_kernel<<<NN, 256, 0, stream>>>(nv1, nv2, adp);

  for (int b0 = 0; b0 < 8; b0 += g) {
    start_conv_kernel<<<dim3(2, 256, g), 256, 0, stream>>>(x, start_w, start_b, hA, b0);
    float* hprev = hA;
    int Lp = 256;
    for (int i = 0; i < 8; i++) {
      int L = Lp >> 1;  // 128,64,32,16,8,4,2,1
      float* hout = (i & 1) ? hA : hB;
      dconv_kernel<<<dim3(2, L, g), 256, 0, stream>>>(
          hprev, filt_w + i * 2048, filt_b + i * 32, gate_w + i * 2048, gate_b + i * 32,
          FG, tap + (size_t)i * 8 * 32 * NN, Lp, L, b0);
      if (i < 7) {  // layer 8's graph conv is dead code (only its skip tap survives)
        chanmix_kernel<0><<<dim3(2, L, g), 256, 0, stream>>>(
            FG, gcn_w + i * 5120, gcn_b + i * 32, hprev, hout, P1, P2, L, Lp);
        int M = g * 32 * L;
        dim3 ggrid(4, (M + 127) / 128);
        // A0 chain: ((W2 FG) A0 + W1 FG) A0 accumulated into H
        gemm_acc<<<ggrid, 256, 0, stream>>>(P2, A0, P1, P1, M, NN, NN, nullptr, nullptr, L);
        gemm_acc<<<ggrid, 256, 0, stream>>>(P1, A0, hout, hout, M, NN, NN, nullptr, nullptr, L);
        // adp chain, BN fused into the last GEMM
        chanmix_kernel<1><<<dim3(2, L, g), 256, 0, stream>>>(
            FG, gcn_w + i * 5120, nullptr, nullptr, nullptr, P1, P2, L, Lp);
        gemm_acc<<<ggrid, 256, 0, stream>>>(P2, adp, P1, P1, M, NN, NN, nullptr, nullptr, L);
        gemm_acc<<<ggrid, 256, 0, stream>>>(P1, adp, hout, hout, M, NN, NN, bn_g + i * 32, bn_b + i * 32, L);
        hprev = hout;
        Lp = L;
      }
    }
  }
  final_kernel<<<dim3(125, 8), 256, 0, stream>>>(tap, skip_w, skip_b, e1w, e1b, e2w, e2b, out);
}

// Round 2
// 9302.691 us; speedup vs baseline: 1.0584x; 1.0584x over previous
//
#include <hip/hip_runtime.h>
#include <cstdint>
#include <cstddef>

#define NN 500

// ---------------------------------------------------------------------------
// adp = softmax(relu(E1 @ E2), axis=1)   E1:[500,10] E2:[10,500] -> adp[500,500]
__global__ __launch_bounds__(256) void adp_kernel(const float* __restrict__ e1,
                                                  const float* __restrict__ e2,
                                                  float* __restrict__ adp) {
  int r = blockIdx.x;
  int tid = threadIdx.x;
  __shared__ float red[256];
  __shared__ float e1row[16];
  if (tid < 10) e1row[tid] = e1[r * 10 + tid];
  __syncthreads();
  float z0, z1 = 0.f;
  {
    float acc = 0.f;
#pragma unroll
    for (int k = 0; k < 10; k++) acc += e1row[k] * e2[k * NN + tid];
    z0 = fmaxf(acc, 0.f);
  }
  bool has1 = (tid + 256) < NN;
  if (has1) {
    float acc = 0.f;
#pragma unroll
    for (int k = 0; k < 10; k++) acc += e1row[k] * e2[k * NN + tid + 256];
    z1 = fmaxf(acc, 0.f);
  }
  float mx = has1 ? fmaxf(z0, z1) : z0;
  red[tid] = mx;
  __syncthreads();
  for (int s = 128; s > 0; s >>= 1) {
    if (tid < s) red[tid] = fmaxf(red[tid], red[tid + s]);
    __syncthreads();
  }
  mx = red[0];
  __syncthreads();
  float ex0 = __expf(z0 - mx);
  float ex1 = has1 ? __expf(z1 - mx) : 0.f;
  red[tid] = ex0 + ex1;
  __syncthreads();
  for (int s = 128; s > 0; s >>= 1) {
    if (tid < s) red[tid] += red[tid + s];
    __syncthreads();
  }
  float inv = 1.f / red[0];
  adp[r * NN + tid] = ex0 * inv;
  if (has1) adp[r * NN + tid + 256] = ex1 * inv;
}

// ---------------------------------------------------------------------------
// h0[bb,c,t,n] = start_w[c,0]*x[b,0,n,t] + start_w[c,1]*x[b,1,n,t] + start_b[c]
__global__ __launch_bounds__(256) void start_conv_kernel(const float* __restrict__ x,
    const float* __restrict__ w, const float* __restrict__ bias,
    float* __restrict__ h0, int b0) {
  int nc = blockIdx.x, t = blockIdx.y, bb = blockIdx.z;
  int n = nc * 256 + threadIdx.x;
  if (n >= NN) return;
  int babs = b0 + bb;
  float x0 = x[(((size_t)babs * 2 + 0) * NN + n) * 256 + t];
  float x1 = x[(((size_t)babs * 2 + 1) * NN + n) * 256 + t];
#pragma unroll
  for (int c = 0; c < 32; c++) {
    h0[(((size_t)bb * 32 + c) * 256 + t) * NN + n] = bias[c] + w[c * 2] * x0 + w[c * 2 + 1] * x1;
  }
}

// ---------------------------------------------------------------------------
// Dilated conv + tanh*sigmoid gating on compact time axis.
// NOTE: every loop touching accf/accg is FULLY unrolled — a partial unroll
// makes the index dynamic and demotes the arrays to scratch (round-0 bug:
// VGPR_Count=44 + 30ms dispatch). Channels processed in 2 halves of 16 so
// 32 accumulators fit without pressure.
__global__ __launch_bounds__(256) void dconv_kernel(const float* __restrict__ hprev,
    const float* __restrict__ fw, const float* __restrict__ fb,
    const float* __restrict__ gw, const float* __restrict__ gb,
    float* __restrict__ FG, float* __restrict__ tapL,
    int Lp, int L, int b0) {
  int nc = blockIdx.x, j = blockIdx.y, bb = blockIdx.z;
  int n = nc * 256 + threadIdx.x;
  if (n >= NN) return;
  size_t base = ((size_t)(bb * 32) * Lp + 2 * j) * NN + n;
  size_t cs = (size_t)Lp * NN;
  bool last = (j == L - 1);
  size_t obase = ((size_t)(bb * 32) * L + j) * NN + n;
  size_t ocs = (size_t)L * NN;
  size_t tbase = ((size_t)(b0 + bb) * 32) * NN + n;
#pragma unroll
  for (int half = 0; half < 2; half++) {
    float accf[16], accg[16];
#pragma unroll
    for (int c = 0; c < 16; c++) {
      accf[c] = fb[half * 16 + c];
      accg[c] = gb[half * 16 + c];
    }
    for (int cp = 0; cp < 32; cp++) {
      float v0 = hprev[base + cp * cs];
      float v1 = hprev[base + cp * cs + NN];
      const float* fwp = fw + (half * 16) * 64 + cp * 2;  // [c][cp][tap]
      const float* gwp = gw + (half * 16) * 64 + cp * 2;
#pragma unroll
      for (int c = 0; c < 16; c++) {
        accf[c] = fmaf(fwp[c * 64], v0, accf[c]);
        accf[c] = fmaf(fwp[c * 64 + 1], v1, accf[c]);
        accg[c] = fmaf(gwp[c * 64], v0, accg[c]);
        accg[c] = fmaf(gwp[c * 64 + 1], v1, accg[c]);
      }
    }
#pragma unroll
    for (int c = 0; c < 16; c++) {
      int co = half * 16 + c;
      float E = __expf(2.f * accf[c]);
      float th = 1.f - 2.f / (E + 1.f);          // tanh
      float sg = 1.f / (1.f + __expf(-accg[c])); // sigmoid
      float v = th * sg;
      FG[obase + (size_t)co * ocs] = v;
      if (last) tapL[tbase + (size_t)co * NN] = v;
    }
  }
}

// ---------------------------------------------------------------------------
// Channel mixes of the GCN, exploiting (Wc X) A == Wc (X A).
// All register-array loops fully unrolled (same scratch-demotion hazard).
template <int VAR>
__global__ __launch_bounds__(256) void chanmix_kernel(const float* __restrict__ FG,
    const float* __restrict__ gw, const float* __restrict__ gb,
    const float* __restrict__ hprev,
    float* __restrict__ H, float* __restrict__ P1, float* __restrict__ P2,
    int L, int Lp) {
  int nc = blockIdx.x, j = blockIdx.y, bb = blockIdx.z;
  int n = nc * 256 + threadIdx.x;
  if (n >= NN) return;
  float fgv[32];
  size_t base = ((size_t)(bb * 32) * L + j) * NN + n;
  size_t cs = (size_t)L * NN;
#pragma unroll
  for (int cp = 0; cp < 32; cp++) fgv[cp] = FG[base + cp * cs];
#pragma unroll
  for (int c = 0; c < 32; c++) {
    const float* wr = gw + c * 160;
    if (VAR == 0) {
      float a0 = gb[c], a1 = 0.f, a2 = 0.f;
#pragma unroll
      for (int cp = 0; cp < 32; cp++) {
        float f = fgv[cp];
        a0 = fmaf(wr[cp], f, a0);
        a1 = fmaf(wr[32 + cp], f, a1);
        a2 = fmaf(wr[64 + cp], f, a2);
      }
      a0 += hprev[((size_t)(bb * 32 + c) * Lp + 2 * j + 1) * NN + n]; // residual
      H[base + c * cs] = a0;
      P1[base + c * cs] = a1;
      P2[base + c * cs] = a2;
    } else {
      float a3 = 0.f, a4 = 0.f;
#pragma unroll
      for (int cp = 0; cp < 32; cp++) {
        float f = fgv[cp];
        a3 = fmaf(wr[96 + cp], f, a3);
        a4 = fmaf(wr[128 + cp], f, a4);
      }
      P1[base + c * cs] = a3;
      P2[base + c * cs] = a4;
    }
  }
}

// ---------------------------------------------------------------------------
// Cout[m,n] = sum_k A[m,k]*B[k,n] + Cin[m,n]   (optional BN epilogue)
// 128x128 block tile, 8x8 per thread, BK=16 staged in LDS.
__global__ __launch_bounds__(256) void gemm_acc(const float* __restrict__ A,
    const float* __restrict__ Bmat, const float* Cin, float* Cout,
    int M, int K, int Nw,
    const float* __restrict__ bng, const float* __restrict__ bnb, int Lc) {
  __shared__ float As[16][132];  // [k][m], +4 pad
  __shared__ float Bs[16][132];  // [k][n]
  int tid = threadIdx.x;
  int bm = blockIdx.y * 128, bn = blockIdx.x * 128;
  int ty = tid >> 4, tx = tid & 15;
  float acc[8][8];
#pragma unroll
  for (int i = 0; i < 8; i++)
#pragma unroll
    for (int j2 = 0; j2 < 8; j2++) acc[i][j2] = 0.f;

  int kTiles = (K + 15) / 16;
  for (int kt = 0; kt < kTiles; kt++) {
    int k0 = kt * 16;
    {
      int kl = tid & 15, m8 = tid >> 4;
      int k = k0 + kl;
      bool kok = k < K;
#pragma unroll
      for (int r = 0; r < 8; r++) {
        int m = bm + m8 * 8 + r;
        As[kl][m8 * 8 + r] = (kok && m < M) ? A[(size_t)m * K + k] : 0.f;
      }
    }
    {
      int n4 = (tid & 31) * 4;
      int kl = tid >> 5;
#pragma unroll
      for (int h = 0; h < 2; h++) {
        int k = k0 + kl + h * 8;
        int n = bn + n4;
        float4 v = make_float4(0.f, 0.f, 0.f, 0.f);
        if (k < K && n < Nw) v = *reinterpret_cast<const float4*>(Bmat + (size_t)k * Nw + n);
        *reinterpret_cast<float4*>(&Bs[kl + h * 8][n4]) = v;
      }
    }
    __syncthreads();
#pragma unroll
    for (int k = 0; k < 16; k++) {
      float4 a0 = *reinterpret_cast<const float4*>(&As[k][ty * 8]);
      float4 a1 = *reinterpret_cast<const float4*>(&As[k][ty * 8 + 4]);
      float4 b0 = *reinterpret_cast<const float4*>(&Bs[k][tx * 8]);
      float4 b1 = *reinterpret_cast<const float4*>(&Bs[k][tx * 8 + 4]);
      float av[8] = {a0.x, a0.y, a0.z, a0.w, a1.x, a1.y, a1.z, a1.w};
      float bv[8] = {b0.x, b0.y, b0.z, b0.w, b1.x, b1.y, b1.z, b1.w};
#pragma unroll
      for (int i = 0; i < 8; i++)
#pragma unroll
        for (int j2 = 0; j2 < 8; j2++) acc[i][j2] = fmaf(av[i], bv[j2], acc[i][j2]);
    }
    __syncthreads();
  }
  bool dobn = (bng != nullptr);
#pragma unroll
  for (int i = 0; i < 8; i++) {
    int m = bm + ty * 8 + i;
    if (m >= M) continue;
    float scale = 1.f, bias = 0.f;
    if (dobn) {
      int c = (m / Lc) & 31;  // m = (bb*32+c)*L + j  ->  (m/L)%32 == c
      scale = bng[c] * rsqrtf(1.0f + 1e-5f);
      bias = bnb[c];
    }
#pragma unroll
    for (int j2 = 0; j2 < 8; j2++) {
      int n = bn + tx * 8 + j2;
      if (n < Nw) {
        float v = acc[i][j2] + Cin[(size_t)m * Nw + n];
        if (dobn) v = v * scale + bias;
        Cout[(size_t)m * Nw + n] = v;
      }
    }
  }
}

// ---------------------------------------------------------------------------
// skip = sum_i (skip_w[i] @ tap[i] + skip_b[i]); out = end2(relu(end1(relu(skip))))
// One block per (b, NB n-values). NB=20 amortizes the per-lane strided weight
// reads (20 FMA per scalar weight load) and cuts weight re-reads 5x vs NB=4.
#define NB 20
#define NBP 21  // +1 pad: 21 coprime with 32 banks
__global__ __launch_bounds__(256) void final_kernel(const float* __restrict__ tap,
    const float* __restrict__ skw, const float* __restrict__ skb,
    const float* __restrict__ e1w, const float* __restrict__ e1b,
    const float* __restrict__ e2w, const float* __restrict__ e2b,
    float* __restrict__ out) {
  __shared__ float tapS[256][NBP];
  __shared__ float skS[256][NBP];
  __shared__ float e1S[512][NBP];
  int tid = threadIdx.x;
  int b = blockIdx.y;
  int n0 = blockIdx.x * NB;
  {
    int i = tid >> 5, c = tid & 31;
    const float* tp = tap + (((size_t)i * 8 + b) * 32 + c) * NN + n0;
#pragma unroll
    for (int v = 0; v < NB; v++) tapS[tid][v] = tp[v];
  }
  __syncthreads();
  {
    float bsum = 0.f;
#pragma unroll
    for (int i2 = 0; i2 < 8; i2++) bsum += skb[i2 * 256 + tid];
    float acc[NB];
#pragma unroll
    for (int v = 0; v < NB; v++) acc[v] = bsum;
#pragma unroll
    for (int i2 = 0; i2 < 8; i2++) {
      const float* wr = skw + ((size_t)i2 * 256 + tid) * 32;
#pragma unroll
      for (int cp = 0; cp < 32; cp++) {
        float w = wr[cp];
#pragma unroll
        for (int v = 0; v < NB; v++) acc[v] = fmaf(w, tapS[i2 * 32 + cp][v], acc[v]);
      }
    }
#pragma unroll
    for (int v = 0; v < NB; v++) skS[tid][v] = fmaxf(acc[v], 0.f);
  }
  __syncthreads();
#pragma unroll
  for (int h = 0; h < 2; h++) {
    int k = tid + h * 256;
    float bv = e1b[k];
    float acc[NB];
#pragma unroll
    for (int v = 0; v < NB; v++) acc[v] = bv;
    const float* wr = e1w + (size_t)k * 256;
    for (int o = 0; o < 256; o++) {
      float w = wr[o];
#pragma unroll
      for (int v = 0; v < NB; v++) acc[v] = fmaf(w, skS[o][v], acc[v]);
    }
#pragma unroll
    for (int v = 0; v < NB; v++) e1S[k][v] = fmaxf(acc[v], 0.f);
  }
  __syncthreads();
  if (tid < 12 * NB) {
    int q = tid / NB, v = tid % NB;
    float acc = e2b[q];
    const float* wr = e2w + (size_t)q * 512;
#pragma unroll 8
    for (int k = 0; k < 512; k++) acc = fmaf(wr[k], e1S[k][v], acc);
    out[((size_t)b * 12 + q) * NN + n0 + v] = acc;
  }
}

// ---------------------------------------------------------------------------
extern "C" void kernel_launch(void* const* d_in, const int* in_sizes, int n_in,
                              void* d_out, int out_size, void* d_ws, size_t ws_size,
                              hipStream_t stream) {
  const float* x       = (const float*)d_in[0];
  const float* A0      = (const float*)d_in[1];
  const float* start_w = (const float*)d_in[2];
  const float* start_b = (const float*)d_in[3];
  const float* filt_w  = (const float*)d_in[4];
  const float* filt_b  = (const float*)d_in[5];
  const float* gate_w  = (const float*)d_in[6];
  const float* gate_b  = (const float*)d_in[7];
  const float* skip_w  = (const float*)d_in[8];
  const float* skip_b  = (const float*)d_in[9];
  const float* gcn_w   = (const float*)d_in[10];
  const float* gcn_b   = (const float*)d_in[11];
  const float* bn_g    = (const float*)d_in[12];
  const float* bn_b    = (const float*)d_in[13];
  const float* nv1     = (const float*)d_in[14];
  const float* nv2     = (const float*)d_in[15];
  const float* e1w     = (const float*)d_in[16];
  const float* e1b     = (const float*)d_in[17];
  const float* e2w     = (const float*)d_in[18];
  const float* e2b     = (const float*)d_in[19];
  float* out = (float*)d_out;

  char* ws = (char*)d_ws;
  size_t off = 0;
  auto alloc = [&](size_t bytes) -> float* {
    float* p = (float*)(ws + off);
    off += (bytes + 255) & ~(size_t)255;
    return p;
  };
  float* adp = alloc((size_t)NN * NN * 4);
  float* tap = alloc((size_t)8 * 8 * 32 * NN * 4);
  size_t fixed = off;
  // per-batch-group buffers: hA (L=256) + hB/FG/P1/P2 (L=128)
  int g = 8;
  while (g > 1 && fixed + (size_t)g * 49152000ull + 8192 > ws_size) g >>= 1;
  float* hA = alloc((size_t)g * 32 * 256 * NN * 4);
  float* hB = alloc((size_t)g * 32 * 128 * NN * 4);
  float* FG = alloc((size_t)g * 32 * 128 * NN * 4);
  float* P1 = alloc((size_t)g * 32 * 128 * NN * 4);
  float* P2 = alloc((size_t)g * 32 * 128 * NN * 4);

  adp_kernel<<<NN, 256, 0, stream>>>(nv1, nv2, adp);

  for (int b0 = 0; b0 < 8; b0 += g) {
    start_conv_kernel<<<dim3(2, 256, g), 256, 0, stream>>>(x, start_w, start_b, hA, b0);
    float* hprev = hA;
    int Lp = 256;
    for (int i = 0; i < 8; i++) {
      int L = Lp >> 1;  // 128,64,32,16,8,4,2,1
      float* hout = (i & 1) ? hA : hB;
      dconv_kernel<<<dim3(2, L, g), 256, 0, stream>>>(
          hprev, filt_w + i * 2048, filt_b + i * 32, gate_w + i * 2048, gate_b + i * 32,
          FG, tap + (size_t)i * 8 * 32 * NN, Lp, L, b0);
      if (i < 7) {  // layer 8's graph conv is dead code (only its skip tap survives)
        chanmix_kernel<0><<<dim3(2, L, g), 256, 0, stream>>>(
            FG, gcn_w + i * 5120, gcn_b + i * 32, hprev, hout, P1, P2, L, Lp);
        int M = g * 32 * L;
        dim3 ggrid(4, (M + 127) / 128);
        // A0 chain: ((W2 FG) A0 + W1 FG) A0 accumulated into H
        gemm_acc<<<ggrid, 256, 0, stream>>>(P2, A0, P1, P1, M, NN, NN, nullptr, nullptr, L);
        gemm_acc<<<ggrid, 256, 0, stream>>>(P1, A0, hout, hout, M, NN, NN, nullptr, nullptr, L);
        // adp chain, BN fused into the last GEMM
        chanmix_kernel<1><<<dim3(2, L, g), 256, 0, stream>>>(
            FG, gcn_w + i * 5120, nullptr, nullptr, nullptr, P1, P2, L, Lp);
        gemm_acc<<<ggrid, 256, 0, stream>>>(P2, adp, P1, P1, M, NN, NN, nullptr, nullptr, L);
        gemm_acc<<<ggrid, 256, 0, stream>>>(P1, adp, hout, hout, M, NN, NN, bn_g + i * 32, bn_b + i * 32, L);
        hprev = hout;
        Lp = L;
      }
    }
  }
  final_kernel<<<dim3(125 / 5, 8), 256, 0, stream>>>(tap, skip_w, skip_b, e1w, e1b, e2w, e2b, out);
}

// Round 4
// 5551.685 us; speedup vs baseline: 1.7734x; 1.6757x over previous
//
#include <hip/hip_runtime.h>
#include <cstdint>
#include <cstddef>

#define NN 500
#define KP 512   // node dim padded to 512 for f16 MFMA operands

typedef _Float16 f16;
typedef _Float16 half8 __attribute__((ext_vector_type(8)));
typedef float floatx4 __attribute__((ext_vector_type(4)));

// A GEMM batch: Out = sum_p A[p] * B[p]^T + Cin. All operands f16 hi/lo pairs
// except fp32 Cin/Out in OUTMODE 1.
struct GemmSet {
  const f16* A[6];
  const f16* B[6];
  const void* Cin;      // OUTMODE0: f16 hi; OUTMODE1: fp32 [M x 500]
  const f16* CinLo;     // OUTMODE0 only
  void* Out;            // OUTMODE0: f16 hi; OUTMODE1: fp32
  f16* OutLo;           // OUTMODE0 only
  int M;
  int npass;
};

// ---------------------------------------------------------------------------
// adp = softmax(relu(E1 @ E2), axis=1)
__global__ __launch_bounds__(256) void adp_kernel(const float* __restrict__ e1,
                                                  const float* __restrict__ e2,
                                                  float* __restrict__ adp) {
  int r = blockIdx.x;
  int tid = threadIdx.x;
  __shared__ float red[256];
  __shared__ float e1row[16];
  if (tid < 10) e1row[tid] = e1[r * 10 + tid];
  __syncthreads();
  float z0, z1 = 0.f;
  {
    float acc = 0.f;
#pragma unroll
    for (int k = 0; k < 10; k++) acc += e1row[k] * e2[k * NN + tid];
    z0 = fmaxf(acc, 0.f);
  }
  bool has1 = (tid + 256) < NN;
  if (has1) {
    float acc = 0.f;
#pragma unroll
    for (int k = 0; k < 10; k++) acc += e1row[k] * e2[k * NN + tid + 256];
    z1 = fmaxf(acc, 0.f);
  }
  float mx = has1 ? fmaxf(z0, z1) : z0;
  red[tid] = mx;
  __syncthreads();
  for (int s = 128; s > 0; s >>= 1) {
    if (tid < s) red[tid] = fmaxf(red[tid], red[tid + s]);
    __syncthreads();
  }
  mx = red[0];
  __syncthreads();
  float ex0 = __expf(z0 - mx);
  float ex1 = has1 ? __expf(z1 - mx) : 0.f;
  red[tid] = ex0 + ex1;
  __syncthreads();
  for (int s = 128; s > 0; s >>= 1) {
    if (tid < s) red[tid] += red[tid + s];
    __syncthreads();
  }
  float inv = 1.f / red[0];
  adp[r * NN + tid] = ex0 * inv;
  if (has1) adp[r * NN + tid + 256] = ex1 * inv;
}

// ---------------------------------------------------------------------------
// B^T as f16 hi/lo pair: hi[w][v]+lo[w][v] ~= src[v][w], 512x512 zero-padded.
__global__ __launch_bounds__(256) void bt_kernel(const float* __restrict__ src,
                                                 f16* __restrict__ hi,
                                                 f16* __restrict__ lo) {
  int idx = blockIdx.x * 256 + threadIdx.x;  // 512*512 total
  int w = idx >> 9, v = idx & 511;
  float x = (w < NN && v < NN) ? src[v * NN + w] : 0.f;
  f16 h = (f16)x;
  hi[idx] = h;
  lo[idx] = (f16)(x - (float)h);
}

// ---------------------------------------------------------------------------
// Zero the pad columns [500,512) of the eight f16 P arrays (ws re-poisoned 0xAA).
__global__ __launch_bounds__(256) void padzero_kernel(uint32_t* __restrict__ slab, int R) {
  int idx = blockIdx.x * 256 + threadIdx.x;
  int total = 8 * R * 6;
  if (idx >= total) return;
  int a = idx / (R * 6);
  int rem = idx - a * R * 6;
  int row = rem / 6;
  int q = rem - row * 6;
  slab[(size_t)a * R * 256 + (size_t)row * 256 + 250 + q] = 0u;
}

// ---------------------------------------------------------------------------
__global__ __launch_bounds__(256) void start_conv_kernel(const float* __restrict__ x,
    const float* __restrict__ w, const float* __restrict__ bias,
    float* __restrict__ h0, int b0) {
  int nc = blockIdx.x, t = blockIdx.y, bb = blockIdx.z;
  int n = nc * 256 + threadIdx.x;
  if (n >= NN) return;
  int babs = b0 + bb;
  float x0 = x[(((size_t)babs * 2 + 0) * NN + n) * 256 + t];
  float x1 = x[(((size_t)babs * 2 + 1) * NN + n) * 256 + t];
#pragma unroll
  for (int c = 0; c < 32; c++) {
    h0[(((size_t)bb * 32 + c) * 256 + t) * NN + n] = bias[c] + w[c * 2] * x0 + w[c * 2 + 1] * x1;
  }
}

// ---------------------------------------------------------------------------
// Fused dilated-conv + gating + GCN channel-mix. FG lives in registers only.
// Outputs: Hout fp32 (hop-2 Cin), and P1a/P2a/P1b/P2b as f16 hi/lo pairs.
// All register-array loops fully unrolled (scratch-demotion hazard, round-1).
__global__ __launch_bounds__(256) void dcm_kernel(
    const float* __restrict__ hprev,
    const float* __restrict__ fw, const float* __restrict__ fb,
    const float* __restrict__ gw, const float* __restrict__ gb,
    const float* __restrict__ cw, const float* __restrict__ cb,
    float* __restrict__ Hout,
    f16* __restrict__ P1aH, f16* __restrict__ P1aL,
    f16* __restrict__ P2aH, f16* __restrict__ P2aL,
    f16* __restrict__ P1bH, f16* __restrict__ P1bL,
    f16* __restrict__ P2bH, f16* __restrict__ P2bL,
    float* __restrict__ tapL,
    int Lp, int L, int b0) {
  int nc = blockIdx.x, j = blockIdx.y, bb = blockIdx.z;
  int n = nc * 256 + threadIdx.x;
  if (n >= NN) return;
  size_t base = ((size_t)(bb * 32) * Lp + 2 * j) * NN + n;
  size_t cs = (size_t)Lp * NN;
  float FG[32];
#pragma unroll
  for (int half = 0; half < 2; half++) {
    float accf[16], accg[16];
#pragma unroll
    for (int c = 0; c < 16; c++) {
      accf[c] = fb[half * 16 + c];
      accg[c] = gb[half * 16 + c];
    }
    for (int cp = 0; cp < 32; cp++) {
      float v0 = hprev[base + cp * cs];
      float v1 = hprev[base + cp * cs + NN];
      const float* fwp = fw + (half * 16) * 64 + cp * 2;  // [c][cp][tap]
      const float* gwp = gw + (half * 16) * 64 + cp * 2;
#pragma unroll
      for (int c = 0; c < 16; c++) {
        accf[c] = fmaf(fwp[c * 64], v0, accf[c]);
        accf[c] = fmaf(fwp[c * 64 + 1], v1, accf[c]);
        accg[c] = fmaf(gwp[c * 64], v0, accg[c]);
        accg[c] = fmaf(gwp[c * 64 + 1], v1, accg[c]);
      }
    }
#pragma unroll
    for (int c = 0; c < 16; c++) {
      float E = __expf(2.f * accf[c]);
      float th = 1.f - 2.f / (E + 1.f);          // tanh
      float sg = 1.f / (1.f + __expf(-accg[c])); // sigmoid
      FG[half * 16 + c] = th * sg;
    }
  }
  if (j == L - 1) {
    size_t tbase = ((size_t)(b0 + bb) * 32) * NN + n;
#pragma unroll
    for (int c = 0; c < 32; c++) tapL[tbase + (size_t)c * NN] = FG[c];
  }
  if (Hout == nullptr) return;  // layer 8: only the skip tap survives
#pragma unroll 2
  for (int c = 0; c < 32; c++) {
    const float* wr = cw + c * 160;
    float h = cb[c], p1 = 0.f, p2 = 0.f, q1 = 0.f, q2 = 0.f;
#pragma unroll
    for (int cp = 0; cp < 32; cp++) {
      float f = FG[cp];
      h  = fmaf(wr[cp], f, h);
      p1 = fmaf(wr[32 + cp], f, p1);
      p2 = fmaf(wr[64 + cp], f, p2);
      q1 = fmaf(wr[96 + cp], f, q1);
      q2 = fmaf(wr[128 + cp], f, q2);
    }
    h += hprev[((size_t)(bb * 32 + c) * Lp + 2 * j + 1) * NN + n];  // residual
    size_t mi = (size_t)(bb * 32 + c) * L + j;
    Hout[mi * NN + n] = h;
    size_t o = mi * KP + n;
    f16 t;
    t = (f16)p1; P1aH[o] = t; P1aL[o] = (f16)(p1 - (float)t);
    t = (f16)p2; P2aH[o] = t; P2aL[o] = (f16)(p2 - (float)t);
    t = (f16)q1; P1bH[o] = t; P1bL[o] = (f16)(q1 - (float)t);
    t = (f16)q2; P2bH[o] = t; P2bL[o] = (f16)(q2 - (float)t);
  }
}

// ---------------------------------------------------------------------------
// MFMA fp16-pair GEMM: Out[m,w] = sum_p sum_v A_p[m,v] * B_p[w,v] + Cin[m,w]
// Block 128m x 64n, 4 waves of 64m x 32n (4x2 subtiles of 16x16, mfma 16x16x32).
// OUTMODE 0: Cin/Out are f16 hi/lo pairs [M x 512] (in-place safe: same-thread RMW).
// OUTMODE 1: fp32 [M x 500] with BN epilogue, in-place on Cin.
template <int OUTMODE>
__global__ __launch_bounds__(256) void mfma_gemm(GemmSet s0, GemmSet s1,
    const float* __restrict__ bng, const float* __restrict__ bnb, int lshift) {
  const GemmSet& s = (blockIdx.z == 0) ? s0 : s1;
  int tid = threadIdx.x;
  int wave = tid >> 6, lane = tid & 63;
  int wm = wave & 1, wn = wave >> 1;
  int m0 = blockIdx.y * 128 + wm * 64;
  int n0 = blockIdx.x * 64 + wn * 32;
  int lm = lane & 15, kq = lane >> 4;  // operand frag: row lm, k-quad kq (8 k each)
  int M = s.M;
  floatx4 acc[4][2];
#pragma unroll
  for (int i = 0; i < 4; i++)
#pragma unroll
    for (int j = 0; j < 2; j++) acc[i][j] = (floatx4){0.f, 0.f, 0.f, 0.f};
  size_t arow[4];
#pragma unroll
  for (int i = 0; i < 4; i++) {
    int r = m0 + i * 16 + lm;
    arow[i] = (size_t)(r < M ? r : M - 1) * KP + kq * 8;
  }
  size_t brow[2];
#pragma unroll
  for (int j = 0; j < 2; j++) brow[j] = (size_t)(n0 + j * 16 + lm) * KP + kq * 8;

  for (int p = 0; p < s.npass; p++) {
    const f16* __restrict__ Ap = s.A[p];
    const f16* __restrict__ Bp = s.B[p];
#pragma unroll 2
    for (int k0 = 0; k0 < KP; k0 += 32) {
      half8 av[4], bv[2];
#pragma unroll
      for (int i = 0; i < 4; i++) av[i] = *(const half8*)(Ap + arow[i] + k0);
#pragma unroll
      for (int j = 0; j < 2; j++) bv[j] = *(const half8*)(Bp + brow[j] + k0);
#pragma unroll
      for (int i = 0; i < 4; i++)
#pragma unroll
        for (int j = 0; j < 2; j++)
          acc[i][j] = __builtin_amdgcn_mfma_f32_16x16x32_f16(av[i], bv[j], acc[i][j], 0, 0, 0);
    }
  }
  // C/D layout: col = lane&15, row = (lane>>4)*4 + reg
  int cn = lane & 15, rq = lane >> 4;
  if (OUTMODE == 0) {
    const f16* CinH = (const f16*)s.Cin;
    const f16* CinL = s.CinLo;
    f16* hi = (f16*)s.Out;
    f16* lo = s.OutLo;
#pragma unroll
    for (int i = 0; i < 4; i++) {
#pragma unroll
      for (int r = 0; r < 4; r++) {
        int row = m0 + i * 16 + rq * 4 + r;
        if (row < M) {
#pragma unroll
          for (int j = 0; j < 2; j++) {
            int col = n0 + j * 16 + cn;
            size_t o = (size_t)row * KP + col;
            float v = acc[i][j][r] + (float)CinH[o] + (float)CinL[o];
            f16 h = (f16)v;
            hi[o] = h;
            lo[o] = (f16)(v - (float)h);
          }
        }
      }
    }
  } else {
    const float* CinF = (const float*)s.Cin;
    float* OutF = (float*)s.Out;
    float rs = rsqrtf(1.f + 1e-5f);
#pragma unroll
    for (int i = 0; i < 4; i++) {
#pragma unroll
      for (int r = 0; r < 4; r++) {
        int row = m0 + i * 16 + rq * 4 + r;
        if (row < M) {
          int c = (row >> lshift) & 31;  // m = (bb*32+c)*L + j
          float scale = bng[c] * rs;
          float bias = bnb[c];
#pragma unroll
          for (int j = 0; j < 2; j++) {
            int col = n0 + j * 16 + cn;
            if (col < NN) {
              size_t o = (size_t)row * NN + col;
              OutF[o] = (acc[i][j][r] + CinF[o]) * scale + bias;
            }
          }
        }
      }
    }
  }
}

// ---------------------------------------------------------------------------
// skip -> relu -> end1 -> relu -> end2. One block per (b, 20 n-values).
#define NB 20
#define NBP 21
__global__ __launch_bounds__(256) void final_kernel(const float* __restrict__ tap,
    const float* __restrict__ skw, const float* __restrict__ skb,
    const float* __restrict__ e1w, const float* __restrict__ e1b,
    const float* __restrict__ e2w, const float* __restrict__ e2b,
    float* __restrict__ out) {
  __shared__ float tapS[256][NBP];
  __shared__ float skS[256][NBP];
  __shared__ float e1S[512][NBP];
  int tid = threadIdx.x;
  int b = blockIdx.y;
  int n0 = blockIdx.x * NB;
  {
    int i = tid >> 5, c = tid & 31;
    const float* tp = tap + (((size_t)i * 8 + b) * 32 + c) * NN + n0;
#pragma unroll
    for (int v = 0; v < NB; v++) tapS[tid][v] = tp[v];
  }
  __syncthreads();
  {
    float bsum = 0.f;
#pragma unroll
    for (int i2 = 0; i2 < 8; i2++) bsum += skb[i2 * 256 + tid];
    float acc[NB];
#pragma unroll
    for (int v = 0; v < NB; v++) acc[v] = bsum;
#pragma unroll
    for (int i2 = 0; i2 < 8; i2++) {
      const float* wr = skw + ((size_t)i2 * 256 + tid) * 32;
#pragma unroll
      for (int cp = 0; cp < 32; cp++) {
        float w = wr[cp];
#pragma unroll
        for (int v = 0; v < NB; v++) acc[v] = fmaf(w, tapS[i2 * 32 + cp][v], acc[v]);
      }
    }
#pragma unroll
    for (int v = 0; v < NB; v++) skS[tid][v] = fmaxf(acc[v], 0.f);
  }
  __syncthreads();
#pragma unroll
  for (int h = 0; h < 2; h++) {
    int k = tid + h * 256;
    float bv = e1b[k];
    float acc[NB];
#pragma unroll
    for (int v = 0; v < NB; v++) acc[v] = bv;
    const float* wr = e1w + (size_t)k * 256;
    for (int o = 0; o < 256; o++) {
      float w = wr[o];
#pragma unroll
      for (int v = 0; v < NB; v++) acc[v] = fmaf(w, skS[o][v], acc[v]);
    }
#pragma unroll
    for (int v = 0; v < NB; v++) e1S[k][v] = fmaxf(acc[v], 0.f);
  }
  __syncthreads();
  if (tid < 12 * NB) {
    int q = tid / NB, v = tid % NB;
    float acc = e2b[q];
    const float* wr = e2w + (size_t)q * 512;
#pragma unroll 8
    for (int k = 0; k < 512; k++) acc = fmaf(wr[k], e1S[k][v], acc);
    out[((size_t)b * 12 + q) * NN + n0 + v] = acc;
  }
}

// ---------------------------------------------------------------------------
extern "C" void kernel_launch(void* const* d_in, const int* in_sizes, int n_in,
                              void* d_out, int out_size, void* d_ws, size_t ws_size,
                              hipStream_t stream) {
  const float* x       = (const float*)d_in[0];
  const float* A0      = (const float*)d_in[1];
  const float* start_w = (const float*)d_in[2];
  const float* start_b = (const float*)d_in[3];
  const float* filt_w  = (const float*)d_in[4];
  const float* filt_b  = (const float*)d_in[5];
  const float* gate_w  = (const float*)d_in[6];
  const float* gate_b  = (const float*)d_in[7];
  const float* skip_w  = (const float*)d_in[8];
  const float* skip_b  = (const float*)d_in[9];
  const float* gcn_w   = (const float*)d_in[10];
  const float* gcn_b   = (const float*)d_in[11];
  const float* bn_g    = (const float*)d_in[12];
  const float* bn_b    = (const float*)d_in[13];
  const float* nv1     = (const float*)d_in[14];
  const float* nv2     = (const float*)d_in[15];
  const float* e1w     = (const float*)d_in[16];
  const float* e1b     = (const float*)d_in[17];
  const float* e2w     = (const float*)d_in[18];
  const float* e2b     = (const float*)d_in[19];
  float* out = (float*)d_out;

  char* ws = (char*)d_ws;
  size_t off = 0;
  auto alloc = [&](size_t bytes) -> void* {
    void* p = (void*)(ws + off);
    off += (bytes + 255) & ~(size_t)255;
    return p;
  };
  float* adp   = (float*)alloc((size_t)NN * NN * 4);
  float* tap   = (float*)alloc((size_t)8 * 8 * 32 * NN * 4);
  f16*   A0tH  = (f16*)alloc((size_t)KP * KP * 2);
  f16*   A0tL  = (f16*)alloc((size_t)KP * KP * 2);
  f16*   adptH = (f16*)alloc((size_t)KP * KP * 2);
  f16*   adptL = (f16*)alloc((size_t)KP * KP * 2);
  size_t fixed = off;
  // per-batch: hA fp32 (L<=256) + hB fp32 (L<=128) + 8 f16 arrays [32*128 x 512]
  const size_t perg = 16384000ull + 8192000ull + 8ull * 4194304ull;  // 58.1 MB
  int g = 8;
  while (g > 1 && fixed + (size_t)g * perg + 65536 > ws_size) g >>= 1;
  float* hA  = (float*)alloc((size_t)g * 16384000ull);
  float* hB  = (float*)alloc((size_t)g * 8192000ull);
  f16* slab  = (f16*)alloc(8ull * g * 4194304ull);
  int R = g * 4096;  // rows per f16 array (layer-0 M)
  f16* P1aH = slab + 0ull * R * KP;  // becomes G1 hi in-place after hop1
  f16* P1aL = slab + 1ull * R * KP;  // becomes G1 lo
  f16* P2aH = slab + 2ull * R * KP;
  f16* P2aL = slab + 3ull * R * KP;
  f16* P1bH = slab + 4ull * R * KP;  // becomes G3 hi
  f16* P1bL = slab + 5ull * R * KP;  // becomes G3 lo
  f16* P2bH = slab + 6ull * R * KP;
  f16* P2bL = slab + 7ull * R * KP;

  adp_kernel<<<NN, 256, 0, stream>>>(nv1, nv2, adp);
  bt_kernel<<<1024, 256, 0, stream>>>(A0, A0tH, A0tL);
  bt_kernel<<<1024, 256, 0, stream>>>(adp, adptH, adptL);
  padzero_kernel<<<(48 * R + 255) / 256, 256, 0, stream>>>((uint32_t*)slab, R);

  for (int b0 = 0; b0 < 8; b0 += g) {
    start_conv_kernel<<<dim3(2, 256, g), 256, 0, stream>>>(x, start_w, start_b, hA, b0);
    float* hprev = hA;
    int Lp = 256;
    for (int i = 0; i < 8; i++) {
      int L = Lp >> 1;  // 128,64,...,1
      if (i < 7) {
        float* hout = (i & 1) ? hA : hB;
        dcm_kernel<<<dim3(2, L, g), 256, 0, stream>>>(
            hprev, filt_w + i * 2048, filt_b + i * 32, gate_w + i * 2048, gate_b + i * 32,
            gcn_w + i * 5120, gcn_b + i * 32, hout,
            P1aH, P1aL, P2aH, P2aL, P1bH, P1bL, P2bH, P2bL,
            tap + (size_t)i * 8 * 32 * NN, Lp, L, b0);
        int M = g * 32 * L;
        int Mb = (M + 127) / 128;
        // hop1 (dual-chain, 3-pass fp32-emulated): G1 = P2a*A0 + P1a (in-place pair),
        //                                          G3 = P2b*adp + P1b
        GemmSet sa{}, sb{};
        sa.A[0] = P2aH; sa.B[0] = A0tH;
        sa.A[1] = P2aH; sa.B[1] = A0tL;
        sa.A[2] = P2aL; sa.B[2] = A0tH;
        sa.Cin = P1aH; sa.CinLo = P1aL; sa.Out = P1aH; sa.OutLo = P1aL;
        sa.M = M; sa.npass = 3;
        sb.A[0] = P2bH; sb.B[0] = adptH;
        sb.A[1] = P2bH; sb.B[1] = adptL;
        sb.A[2] = P2bL; sb.B[2] = adptH;
        sb.Cin = P1bH; sb.CinLo = P1bL; sb.Out = P1bH; sb.OutLo = P1bL;
        sb.M = M; sb.npass = 3;
        mfma_gemm<0><<<dim3(8, Mb, 2), 256, 0, stream>>>(sa, sb, nullptr, nullptr, 0);
        // hop2: hout = BN(H + G1*A0 + G3*adp), 3 passes per chain
        GemmSet sc{};
        sc.A[0] = P1aH; sc.B[0] = A0tH;
        sc.A[1] = P1aH; sc.B[1] = A0tL;
        sc.A[2] = P1aL; sc.B[2] = A0tH;
        sc.A[3] = P1bH; sc.B[3] = adptH;
        sc.A[4] = P1bH; sc.B[4] = adptL;
        sc.A[5] = P1bL; sc.B[5] = adptH;
        sc.Cin = hout; sc.Out = hout; sc.M = M; sc.npass = 6;
        mfma_gemm<1><<<dim3(8, Mb, 1), 256, 0, stream>>>(sc, sc, bn_g + i * 32, bn_b + i * 32, 7 - i);
        hprev = hout;
        Lp = L;
      } else {
        // layer 8: only the skip tap survives
        dcm_kernel<<<dim3(2, 1, g), 256, 0, stream>>>(
            hprev, filt_w + i * 2048, filt_b + i * 32, gate_w + i * 2048, gate_b + i * 32,
            gcn_w, gcn_b, nullptr,
            P1aH, P1aL, P2aH, P2aL, P1bH, P1bL, P2bH, P2bL,
            tap + (size_t)i * 8 * 32 * NN, Lp, 1, b0);
      }
    }
  }
  final_kernel<<<dim3(25, 8), 256, 0, stream>>>(tap, skip_w, skip_b, e1w, e1b, e2w, e2b, out);
}